// Round 1
// baseline (565.565 us; speedup 1.0000x reference)
//
#include <hip/hip_runtime.h>

#define N_NODES 4096
#define F_IN 512
#define H_DIM 128
#define C_DIM 16
#define EPSF 1e-8f
#define LOG2E 1.4426950408889634f

typedef __attribute__((ext_vector_type(8))) short bf16x8;
typedef __attribute__((ext_vector_type(4))) float f32x4;

__device__ __forceinline__ ushort f2bf(float f){
  union { float f; unsigned u; } v; v.f = f;
  unsigned u = v.u;
  return (ushort)((u + 0x7fffu + ((u >> 16) & 1u)) >> 16);
}

// ---------------------------------------------------------------------------
// K1: h = x @ W0 for 3 branches; row norms; write hn (bf16, row-major) and
//     hvT (bf16, transposed [3][128][4096]) so flash0's PV B-frags are
//     contiguous 16B loads.
// ---------------------------------------------------------------------------
__global__ __launch_bounds__(128) void proj0_kernel(
    const float* __restrict__ x,
    const float* __restrict__ Wl, const float* __restrict__ Wh,
    const float* __restrict__ Wm,
    ushort* __restrict__ hn, ushort* __restrict__ hvT)
{
  const int t = threadIdx.x;
  const int r0 = blockIdx.x * 8;
  __shared__ float xs[8][F_IN];
  for (int i = t; i < 8 * F_IN; i += 128)
    xs[i >> 9][i & 511] = x[(size_t)(r0 + (i >> 9)) * F_IN + (i & 511)];
  __syncthreads();

  float acc0[8], acc1[8], acc2[8];
#pragma unroll
  for (int r = 0; r < 8; r++) { acc0[r] = 0.f; acc1[r] = 0.f; acc2[r] = 0.f; }

  for (int k = 0; k < F_IN; k++) {
    float wl = Wl[k * H_DIM + t];
    float wh = Wh[k * H_DIM + t];
    float wm = Wm[k * H_DIM + t];
#pragma unroll
    for (int r = 0; r < 8; r++) {
      float xv = xs[r][k];
      acc0[r] = fmaf(xv, wl, acc0[r]);
      acc1[r] = fmaf(xv, wh, acc1[r]);
      acc2[r] = fmaf(xv, wm, acc2[r]);
    }
  }

  __shared__ float red[24][2];
  const int wv = t >> 6;
  const int lane = t & 63;

#define REDUCE_BRANCH(ACC, B)                                        \
  _Pragma("unroll")                                                  \
  for (int r = 0; r < 8; r++) {                                      \
    float v = ACC[r] * ACC[r];                                       \
    v += __shfl_down(v, 32); v += __shfl_down(v, 16);                \
    v += __shfl_down(v, 8);  v += __shfl_down(v, 4);                 \
    v += __shfl_down(v, 2);  v += __shfl_down(v, 1);                 \
    if (lane == 0) red[(B) * 8 + r][wv] = v;                         \
  }
  REDUCE_BRANCH(acc0, 0)
  REDUCE_BRANCH(acc1, 1)
  REDUCE_BRANCH(acc2, 2)
  __syncthreads();

#define WRITE_BRANCH(ACC, B)                                                   \
  _Pragma("unroll")                                                            \
  for (int r = 0; r < 8; r++) {                                                \
    float nrm = sqrtf(red[(B) * 8 + r][0] + red[(B) * 8 + r][1]);              \
    float rn = 1.0f / fmaxf(nrm, EPSF);                                        \
    float h = ACC[r];                                                          \
    hn[((size_t)(B) * N_NODES + r0 + r) * H_DIM + t] = f2bf(h * rn);           \
    hvT[((size_t)(B) * H_DIM + t) * N_NODES + r0 + r] = f2bf(h);               \
  }
  WRITE_BRANCH(acc0, 0)
  WRITE_BRANCH(acc1, 1)
  WRITE_BRANCH(acc2, 2)
#undef REDUCE_BRANCH
#undef WRITE_BRANCH
}

// ---------------------------------------------------------------------------
// K2: flash attention, D=128, bf16 MFMA 16x16x32. One wave per block; each
//     wave owns 16 q-rows, loops KV in tiles of 32.
//     S[q][k] = cos(q,k)*log2e + log2(adj+eps); online softmax (base 2);
//     P staged via padded LDS (stride 40 ushorts) to get A-frag layout.
// ---------------------------------------------------------------------------
__global__ __launch_bounds__(64) void flash0_kernel(
    const ushort* __restrict__ hn, const ushort* __restrict__ hvT,
    const float* __restrict__ adj_l, const float* __restrict__ adj_h,
    const float* __restrict__ adj_m,
    float* __restrict__ o0)
{
  const int lane = threadIdx.x;
  const int lr = lane & 15;
  const int lg = lane >> 4;
  const int b = blockIdx.y;
  const int q0 = blockIdx.x * 16;
  const float* adj = (b == 0) ? adj_l : (b == 1) ? adj_h : adj_m;
  const ushort* Q = hn + (size_t)b * N_NODES * H_DIM;
  const ushort* VT = hvT + (size_t)b * H_DIM * N_NODES;

  bf16x8 qf[4];
  {
    const ushort* qp = Q + (size_t)(q0 + lr) * H_DIM + lg * 8;
#pragma unroll
    for (int t = 0; t < 4; t++) qf[t] = *(const bf16x8*)(qp + 32 * t);
  }

  f32x4 o[8];
#pragma unroll
  for (int dt = 0; dt < 8; dt++) o[dt] = (f32x4){0.f, 0.f, 0.f, 0.f};
  float m[4]    = {-1e30f, -1e30f, -1e30f, -1e30f};
  float lsum[4] = {0.f, 0.f, 0.f, 0.f};

  __shared__ ushort pbuf[16][40];  // stride 40 ushorts = 80 B (16B-aligned rows)

  const int qrow_base = q0 + lg * 4;

  for (int k0 = 0; k0 < N_NODES; k0 += 32) {
    // --- QK^T (two 16x16 S tiles) ---
    f32x4 s0 = (f32x4){0.f, 0.f, 0.f, 0.f};
    f32x4 s1 = (f32x4){0.f, 0.f, 0.f, 0.f};
    {
      const ushort* kp0 = Q + (size_t)(k0 + lr) * H_DIM + lg * 8;
      const ushort* kp1 = kp0 + 16 * H_DIM;
#pragma unroll
      for (int t = 0; t < 4; t++) {
        bf16x8 kf0 = *(const bf16x8*)(kp0 + 32 * t);
        bf16x8 kf1 = *(const bf16x8*)(kp1 + 32 * t);
        s0 = __builtin_amdgcn_mfma_f32_16x16x32_bf16(qf[t], kf0, s0, 0, 0, 0);
        s1 = __builtin_amdgcn_mfma_f32_16x16x32_bf16(qf[t], kf1, s1, 0, 0, 0);
      }
    }
    // --- bias + online softmax (base-2 domain) ---
    float p0[4], p1[4], scale[4];
#pragma unroll
    for (int r = 0; r < 4; r++) {
      const float* ar = adj + (size_t)(qrow_base + r) * N_NODES + k0;
      float l0 = fmaf(s0[r], LOG2E, log2f(ar[lr] + EPSF));
      float l1 = fmaf(s1[r], LOG2E, log2f(ar[16 + lr] + EPSF));
      float v = fmaxf(l0, l1);
#pragma unroll
      for (int d = 1; d < 16; d <<= 1) v = fmaxf(v, __shfl_xor(v, d));
      float mn = fmaxf(m[r], v);
      scale[r] = exp2f(m[r] - mn);
      p0[r] = exp2f(l0 - mn);
      p1[r] = exp2f(l1 - mn);
      float ps = p0[r] + p1[r];
#pragma unroll
      for (int d = 1; d < 16; d <<= 1) ps += __shfl_xor(ps, d);
      lsum[r] = fmaf(lsum[r], scale[r], ps);
      m[r] = mn;
    }
#pragma unroll
    for (int dt = 0; dt < 8; dt++) {
#pragma unroll
      for (int r = 0; r < 4; r++) o[dt][r] *= scale[r];
    }
    // --- P -> LDS (C/D layout -> A-frag layout round trip) ---
#pragma unroll
    for (int r = 0; r < 4; r++) {
      pbuf[lg * 4 + r][lr]      = f2bf(p0[r]);
      pbuf[lg * 4 + r][16 + lr] = f2bf(p1[r]);
    }
    __syncthreads();
    bf16x8 pf = *(const bf16x8*)&pbuf[lr][lg * 8];
    // --- PV: O[16][128] += P[16][32] @ V[32][128] ---
#pragma unroll
    for (int dt = 0; dt < 8; dt++) {
      const ushort* vp = VT + (size_t)(dt * 16 + lr) * N_NODES + k0 + lg * 8;
      bf16x8 vf = *(const bf16x8*)vp;
      o[dt] = __builtin_amdgcn_mfma_f32_16x16x32_bf16(pf, vf, o[dt], 0, 0, 0);
    }
    __syncthreads();
  }

#pragma unroll
  for (int dt = 0; dt < 8; dt++) {
#pragma unroll
    for (int r = 0; r < 4; r++) {
      o0[((size_t)b * N_NODES + qrow_base + r) * H_DIM + dt * 16 + lr] =
          o[dt][r] / lsum[r];
    }
  }
}

// ---------------------------------------------------------------------------
// K3: h_comb = sum_b softmax(g0)_b * relu(o0_b + b0_b); hb = h_comb @ W1 (x3);
//     row norms over 16 dims -> hn1. One block per row.
// ---------------------------------------------------------------------------
__global__ __launch_bounds__(128) void mix1_kernel(
    const float* __restrict__ o0,
    const float* __restrict__ bl0, const float* __restrict__ bh0,
    const float* __restrict__ bm0,
    const float* __restrict__ Wl1, const float* __restrict__ Wh1,
    const float* __restrict__ Wm1,
    const float* __restrict__ g0,
    float* __restrict__ hb, float* __restrict__ hn1)
{
  const int q = blockIdx.x;
  const int t = threadIdx.x;
  float ga = g0[0], gb = g0[1], gc = g0[2];
  float gm = fmaxf(ga, fmaxf(gb, gc));
  float e0 = expf(ga - gm), e1 = expf(gb - gm), e2 = expf(gc - gm);
  float ei = 1.0f / (e0 + e1 + e2);
  const size_t ND = (size_t)N_NODES * H_DIM;

  __shared__ float hc[H_DIM];
  float v = e0 * ei * fmaxf(o0[(size_t)q * H_DIM + t] + bl0[t], 0.f)
          + e1 * ei * fmaxf(o0[ND + (size_t)q * H_DIM + t] + bh0[t], 0.f)
          + e2 * ei * fmaxf(o0[2 * ND + (size_t)q * H_DIM + t] + bm0[t], 0.f);
  hc[t] = v;
  __syncthreads();

  __shared__ float shb[48];
  if (t < 48) {
    const int b = t >> 4, j = t & 15;
    const float* W = (b == 0) ? Wl1 : (b == 1) ? Wh1 : Wm1;
    float s = 0.f;
    for (int k = 0; k < H_DIM; k++) s = fmaf(hc[k], W[k * C_DIM + j], s);
    shb[t] = s;
  }
  __syncthreads();
  __shared__ float rns[3];
  if (t < 3) {
    float s = 0.f;
#pragma unroll
    for (int j = 0; j < C_DIM; j++) { float u = shb[t * C_DIM + j]; s = fmaf(u, u, s); }
    rns[t] = 1.0f / fmaxf(sqrtf(s), EPSF);
  }
  __syncthreads();
  if (t < 48) {
    const int b = t >> 4, j = t & 15;
    size_t idx = ((size_t)b * N_NODES + q) * C_DIM + j;
    hb[idx] = shb[t];
    hn1[idx] = shb[t] * rns[b];
  }
}

// ---------------------------------------------------------------------------
// K4: flash attention, D=16, f32 vector, thread-per-q-row, K-split 16 ways.
//     K/V chunk staged in LDS. Writes partial (m, l, acc[16]).
// ---------------------------------------------------------------------------
#define KCH 256
__global__ __launch_bounds__(256) void flash1_kernel(
    const float* __restrict__ hn1, const float* __restrict__ hb,
    const float* __restrict__ adj_l, const float* __restrict__ adj_h,
    const float* __restrict__ adj_m,
    float* __restrict__ pm, float* __restrict__ pl, float* __restrict__ pacc)
{
  const int tid = threadIdx.x;
  const int q = blockIdx.x * 256 + tid;
  const int ks = blockIdx.y;
  const int b = blockIdx.z;
  const float* adj = (b == 0) ? adj_l : (b == 1) ? adj_h : adj_m;
  const float* Qn = hn1 + (size_t)b * N_NODES * C_DIM;
  const float* V  = hb  + (size_t)b * N_NODES * C_DIM;

  f32x4 qv[4];
  {
    const f32x4* p = (const f32x4*)(Qn + (size_t)q * C_DIM);
#pragma unroll
    for (int i = 0; i < 4; i++) qv[i] = p[i];
  }

  __shared__ __align__(16) float skn[KCH][C_DIM];
  __shared__ __align__(16) float sv[KCH][C_DIM];
  const int k0 = ks * KCH;
  {
    const f32x4* src1 = (const f32x4*)(Qn + (size_t)k0 * C_DIM);
    const f32x4* src2 = (const f32x4*)(V + (size_t)k0 * C_DIM);
    f32x4* d1 = (f32x4*)&skn[0][0];
    f32x4* d2 = (f32x4*)&sv[0][0];
    for (int i = tid; i < KCH * C_DIM / 4; i += 256) { d1[i] = src1[i]; d2[i] = src2[i]; }
  }
  __syncthreads();

  float m = -1e30f, l = 0.f;
  f32x4 acc[4];
#pragma unroll
  for (int i = 0; i < 4; i++) acc[i] = (f32x4){0.f, 0.f, 0.f, 0.f};

  const float* arow = adj + (size_t)q * N_NODES + k0;
  for (int kk = 0; kk < KCH; kk += 4) {
    f32x4 av = *(const f32x4*)(arow + kk);
#pragma unroll
    for (int u = 0; u < 4; u++) {
      const int k = kk + u;
      float s = 0.f;
#pragma unroll
      for (int i = 0; i < 4; i++) {
        f32x4 kv = ((const f32x4*)&skn[k][0])[i];
        s += qv[i][0] * kv[0] + qv[i][1] * kv[1] + qv[i][2] * kv[2] + qv[i][3] * kv[3];
      }
      s = fmaf(s, LOG2E, log2f(av[u] + EPSF));
      float mn = fmaxf(m, s);
      float sc = exp2f(m - mn);
      float p = exp2f(s - mn);
      m = mn;
      l = fmaf(l, sc, p);
#pragma unroll
      for (int i = 0; i < 4; i++) {
        f32x4 vv = ((const f32x4*)&sv[k][0])[i];
        acc[i] = acc[i] * sc + p * vv;
      }
    }
  }

  const size_t pidx = (size_t)(b * 16 + ks) * N_NODES + q;
  pm[pidx] = m;
  pl[pidx] = l;
  f32x4* pa = (f32x4*)(pacc + pidx * C_DIM);
#pragma unroll
  for (int i = 0; i < 4; i++) pa[i] = acc[i];
}

// ---------------------------------------------------------------------------
// K5: merge the 16 K-split partials per (branch, row).
// ---------------------------------------------------------------------------
__global__ __launch_bounds__(256) void combine1_kernel(
    const float* __restrict__ pm, const float* __restrict__ pl,
    const float* __restrict__ pacc, float* __restrict__ o1)
{
  const int q = blockIdx.x * 256 + threadIdx.x;
  const int b = blockIdx.y;
  float ms[16];
  float M = -1e30f;
#pragma unroll
  for (int ks = 0; ks < 16; ks++) {
    ms[ks] = pm[(size_t)(b * 16 + ks) * N_NODES + q];
    M = fmaxf(M, ms[ks]);
  }
  float L = 0.f;
  f32x4 out0 = (f32x4){0,0,0,0}, out1 = (f32x4){0,0,0,0},
        out2 = (f32x4){0,0,0,0}, out3 = (f32x4){0,0,0,0};
#pragma unroll
  for (int ks = 0; ks < 16; ks++) {
    const size_t pidx = (size_t)(b * 16 + ks) * N_NODES + q;
    float wk = exp2f(ms[ks] - M);
    L = fmaf(wk, pl[pidx], L);
    const f32x4* pa = (const f32x4*)(pacc + pidx * C_DIM);
    out0 += wk * pa[0]; out1 += wk * pa[1]; out2 += wk * pa[2]; out3 += wk * pa[3];
  }
  float invL = 1.0f / L;
  f32x4* dst = (f32x4*)(o1 + ((size_t)b * N_NODES + q) * C_DIM);
  dst[0] = out0 * invL; dst[1] = out1 * invL; dst[2] = out2 * invL; dst[3] = out3 * invL;
}

// ---------------------------------------------------------------------------
// K6: add biases, softmax(g1)-weighted branch mix, log_softmax over 16.
// ---------------------------------------------------------------------------
__global__ __launch_bounds__(256) void final_kernel(
    const float* __restrict__ o1,
    const float* __restrict__ bl1, const float* __restrict__ bh1,
    const float* __restrict__ bm1,
    const float* __restrict__ g1, float* __restrict__ out)
{
  const int q = blockIdx.x * 256 + threadIdx.x;
  float ga = g1[0], gb = g1[1], gc = g1[2];
  float gm = fmaxf(ga, fmaxf(gb, gc));
  float e0 = expf(ga - gm), e1 = expf(gb - gm), e2 = expf(gc - gm);
  float ei = 1.0f / (e0 + e1 + e2);
  float w0 = e0 * ei, w1 = e1 * ei, w2 = e2 * ei;
  const size_t NC = (size_t)N_NODES * C_DIM;

  float v[16];
#pragma unroll
  for (int i = 0; i < 4; i++) {
    f32x4 a = ((const f32x4*)(o1 + (size_t)q * C_DIM))[i];
    f32x4 bA = ((const f32x4*)(o1 + NC + (size_t)q * C_DIM))[i];
    f32x4 c = ((const f32x4*)(o1 + 2 * NC + (size_t)q * C_DIM))[i];
    f32x4 xl = ((const f32x4*)bl1)[i];
    f32x4 xh = ((const f32x4*)bh1)[i];
    f32x4 xm = ((const f32x4*)bm1)[i];
#pragma unroll
    for (int j = 0; j < 4; j++)
      v[i * 4 + j] = w0 * (a[j] + xl[j]) + w1 * (bA[j] + xh[j]) + w2 * (c[j] + xm[j]);
  }
  float mx = -1e30f;
#pragma unroll
  for (int j = 0; j < 16; j++) mx = fmaxf(mx, v[j]);
  float se = 0.f;
#pragma unroll
  for (int j = 0; j < 16; j++) se += expf(v[j] - mx);
  float lse = mx + logf(se);
  f32x4* dst = (f32x4*)(out + (size_t)q * C_DIM);
#pragma unroll
  for (int i = 0; i < 4; i++) {
    f32x4 r;
#pragma unroll
    for (int j = 0; j < 4; j++) r[j] = v[i * 4 + j] - lse;
    dst[i] = r;
  }
}

// ---------------------------------------------------------------------------
extern "C" void kernel_launch(void* const* d_in, const int* in_sizes, int n_in,
                              void* d_out, int out_size, void* d_ws, size_t ws_size,
                              hipStream_t stream) {
  (void)in_sizes; (void)n_in; (void)out_size; (void)ws_size;
  const float* x     = (const float*)d_in[0];
  const float* adj_l = (const float*)d_in[1];
  const float* adj_h = (const float*)d_in[2];
  const float* adj_m = (const float*)d_in[3];
  const float* w_l0  = (const float*)d_in[4];
  const float* b_l0  = (const float*)d_in[5];
  const float* w_h0  = (const float*)d_in[6];
  const float* b_h0  = (const float*)d_in[7];
  const float* w_m0  = (const float*)d_in[8];
  const float* b_m0  = (const float*)d_in[9];
  const float* w_l1  = (const float*)d_in[10];
  const float* b_l1  = (const float*)d_in[11];
  const float* w_h1  = (const float*)d_in[12];
  const float* b_h1  = (const float*)d_in[13];
  const float* w_m1  = (const float*)d_in[14];
  const float* b_m1  = (const float*)d_in[15];
  const float* g0    = (const float*)d_in[16];
  const float* g1    = (const float*)d_in[17];
  float* out = (float*)d_out;

  char* ws = (char*)d_ws;
  ushort* hn  = (ushort*)(ws);                 // 3*4096*128*2  = 3 MB
  ushort* hvT = (ushort*)(ws + 3145728);       // 3 MB
  float*  o0  = (float*)(ws + 6291456);        // 6 MB
  float*  hb  = (float*)(ws + 12582912);       // 768 KB
  float*  hn1 = (float*)(ws + 13369344);       // 768 KB
  float*  pm  = (float*)(ws + 14155776);       // 768 KB
  float*  pl  = (float*)(ws + 14942208);       // 768 KB
  float*  pacc= (float*)(ws + 15728640);       // 12 MB
  float*  o1  = (float*)(ws + 28311552);       // 768 KB  (total ~27.8 MB)

  proj0_kernel<<<dim3(512), dim3(128), 0, stream>>>(x, w_l0, w_h0, w_m0, hn, hvT);
  flash0_kernel<<<dim3(256, 3), dim3(64), 0, stream>>>(hn, hvT, adj_l, adj_h, adj_m, o0);
  mix1_kernel<<<dim3(4096), dim3(128), 0, stream>>>(o0, b_l0, b_h0, b_m0,
                                                    w_l1, w_h1, w_m1, g0, hb, hn1);
  flash1_kernel<<<dim3(16, 16, 3), dim3(256), 0, stream>>>(hn1, hb, adj_l, adj_h, adj_m,
                                                           pm, pl, pacc);
  combine1_kernel<<<dim3(16, 3), dim3(256), 0, stream>>>(pm, pl, pacc, o1);
  final_kernel<<<dim3(16), dim3(256), 0, stream>>>(o1, b_l1, b_h1, b_m1, g1, out);
}

// Round 2
// 402.244 us; speedup vs baseline: 1.4060x; 1.4060x over previous
//
#include <hip/hip_runtime.h>

#define N_NODES 4096
#define F_IN 512
#define H_DIM 128
#define C_DIM 16
#define EPSF 1e-8f
#define LOG2E 1.4426950408889634f
#define KS0 4            // layer-0 flash K-splits
#define KLEN0 (N_NODES / KS0)
#define NT0 (KLEN0 / 32)

typedef __attribute__((ext_vector_type(8))) short bf16x8;
typedef __attribute__((ext_vector_type(4))) float f32x4;

__device__ __forceinline__ ushort f2bf(float f){
  union { float f; unsigned u; } v; v.f = f;
  unsigned u = v.u;
  return (ushort)((u + 0x7fffu + ((u >> 16) & 1u)) >> 16);
}

// ---------------------------------------------------------------------------
// K1: h = x @ W0 for 3 branches; row norms; write hn (bf16, row-major) and
//     hvT (bf16, transposed [3][128][4096]).
// ---------------------------------------------------------------------------
__global__ __launch_bounds__(128) void proj0_kernel(
    const float* __restrict__ x,
    const float* __restrict__ Wl, const float* __restrict__ Wh,
    const float* __restrict__ Wm,
    ushort* __restrict__ hn, ushort* __restrict__ hvT)
{
  const int t = threadIdx.x;
  const int r0 = blockIdx.x * 8;
  __shared__ float xs[8][F_IN];
  for (int i = t; i < 8 * F_IN; i += 128)
    xs[i >> 9][i & 511] = x[(size_t)(r0 + (i >> 9)) * F_IN + (i & 511)];
  __syncthreads();

  float acc0[8], acc1[8], acc2[8];
#pragma unroll
  for (int r = 0; r < 8; r++) { acc0[r] = 0.f; acc1[r] = 0.f; acc2[r] = 0.f; }

  for (int k = 0; k < F_IN; k++) {
    float wl = Wl[k * H_DIM + t];
    float wh = Wh[k * H_DIM + t];
    float wm = Wm[k * H_DIM + t];
#pragma unroll
    for (int r = 0; r < 8; r++) {
      float xv = xs[r][k];
      acc0[r] = fmaf(xv, wl, acc0[r]);
      acc1[r] = fmaf(xv, wh, acc1[r]);
      acc2[r] = fmaf(xv, wm, acc2[r]);
    }
  }

  __shared__ float red[24][2];
  const int wv = t >> 6;
  const int lane = t & 63;

#define REDUCE_BRANCH(ACC, B)                                        \
  _Pragma("unroll")                                                  \
  for (int r = 0; r < 8; r++) {                                      \
    float v = ACC[r] * ACC[r];                                       \
    v += __shfl_down(v, 32); v += __shfl_down(v, 16);                \
    v += __shfl_down(v, 8);  v += __shfl_down(v, 4);                 \
    v += __shfl_down(v, 2);  v += __shfl_down(v, 1);                 \
    if (lane == 0) red[(B) * 8 + r][wv] = v;                         \
  }
  REDUCE_BRANCH(acc0, 0)
  REDUCE_BRANCH(acc1, 1)
  REDUCE_BRANCH(acc2, 2)
  __syncthreads();

#define WRITE_BRANCH(ACC, B)                                                   \
  _Pragma("unroll")                                                            \
  for (int r = 0; r < 8; r++) {                                                \
    float nrm = sqrtf(red[(B) * 8 + r][0] + red[(B) * 8 + r][1]);              \
    float rn = 1.0f / fmaxf(nrm, EPSF);                                        \
    float h = ACC[r];                                                          \
    hn[((size_t)(B) * N_NODES + r0 + r) * H_DIM + t] = f2bf(h * rn);           \
    hvT[((size_t)(B) * H_DIM + t) * N_NODES + r0 + r] = f2bf(h);               \
  }
  WRITE_BRANCH(acc0, 0)
  WRITE_BRANCH(acc1, 1)
  WRITE_BRANCH(acc2, 2)
#undef REDUCE_BRANCH
#undef WRITE_BRANCH
}

// ---------------------------------------------------------------------------
// K2: flash attention layer 0, D=128, bf16 MFMA 16x16x32, K-split KS0 ways.
//     Each wave: 16 q-rows x 1024 K-cols. Writes unnormalized partials
//     (m, l, O[16][128]) in base-2 online-softmax domain.
//     adj values for the NEXT K-tile are prefetched one iteration ahead.
// ---------------------------------------------------------------------------
__global__ __launch_bounds__(64) void flash0_kernel(
    const ushort* __restrict__ hn, const ushort* __restrict__ hvT,
    const float* __restrict__ adj_l, const float* __restrict__ adj_h,
    const float* __restrict__ adj_m,
    float* __restrict__ pm0, float* __restrict__ pl0, float* __restrict__ pO)
{
  const int lane = threadIdx.x;
  const int lr = lane & 15;
  const int lg = lane >> 4;
  const int ks = blockIdx.y;
  const int b = blockIdx.z;
  const int q0 = blockIdx.x * 16;
  const float* adj = (b == 0) ? adj_l : (b == 1) ? adj_h : adj_m;
  const ushort* Q = hn + (size_t)b * N_NODES * H_DIM;
  const ushort* VT = hvT + (size_t)b * H_DIM * N_NODES;
  const int kbase = ks * KLEN0;

  bf16x8 qf[4];
  {
    const ushort* qp = Q + (size_t)(q0 + lr) * H_DIM + lg * 8;
#pragma unroll
    for (int t = 0; t < 4; t++) qf[t] = *(const bf16x8*)(qp + 32 * t);
  }

  f32x4 o[8];
#pragma unroll
  for (int dt = 0; dt < 8; dt++) o[dt] = (f32x4){0.f, 0.f, 0.f, 0.f};
  float m[4]    = {-1e30f, -1e30f, -1e30f, -1e30f};
  float lsum[4] = {0.f, 0.f, 0.f, 0.f};

  __shared__ ushort pbuf[16][40];

  const int qrow_base = q0 + lg * 4;

  const float* ar[4];
#pragma unroll
  for (int r = 0; r < 4; r++)
    ar[r] = adj + (size_t)(qrow_base + r) * N_NODES + kbase;

  float av0[4], av1[4];
#pragma unroll
  for (int r = 0; r < 4; r++) { av0[r] = ar[r][lr]; av1[r] = ar[r][16 + lr]; }

  for (int t = 0; t < NT0; t++) {
    const int k0 = kbase + t * 32;
    // prefetch next tile's adj
    float nv0[4], nv1[4];
    if (t + 1 < NT0) {
#pragma unroll
      for (int r = 0; r < 4; r++) {
        nv0[r] = ar[r][(t + 1) * 32 + lr];
        nv1[r] = ar[r][(t + 1) * 32 + 16 + lr];
      }
    }
    // --- QK^T (two 16x16 S tiles) ---
    f32x4 s0 = (f32x4){0.f, 0.f, 0.f, 0.f};
    f32x4 s1 = (f32x4){0.f, 0.f, 0.f, 0.f};
    {
      const ushort* kp0 = Q + (size_t)(k0 + lr) * H_DIM + lg * 8;
      const ushort* kp1 = kp0 + 16 * H_DIM;
#pragma unroll
      for (int u = 0; u < 4; u++) {
        bf16x8 kf0 = *(const bf16x8*)(kp0 + 32 * u);
        bf16x8 kf1 = *(const bf16x8*)(kp1 + 32 * u);
        s0 = __builtin_amdgcn_mfma_f32_16x16x32_bf16(qf[u], kf0, s0, 0, 0, 0);
        s1 = __builtin_amdgcn_mfma_f32_16x16x32_bf16(qf[u], kf1, s1, 0, 0, 0);
      }
    }
    // --- bias + online softmax (base-2 domain) ---
    float p0[4], p1[4], scale[4];
#pragma unroll
    for (int r = 0; r < 4; r++) {
      float l0 = fmaf(s0[r], LOG2E, log2f(av0[r] + EPSF));
      float l1 = fmaf(s1[r], LOG2E, log2f(av1[r] + EPSF));
      float v = fmaxf(l0, l1);
#pragma unroll
      for (int d = 1; d < 16; d <<= 1) v = fmaxf(v, __shfl_xor(v, d));
      float mn = fmaxf(m[r], v);
      scale[r] = exp2f(m[r] - mn);
      p0[r] = exp2f(l0 - mn);
      p1[r] = exp2f(l1 - mn);
      float ps = p0[r] + p1[r];
#pragma unroll
      for (int d = 1; d < 16; d <<= 1) ps += __shfl_xor(ps, d);
      lsum[r] = fmaf(lsum[r], scale[r], ps);
      m[r] = mn;
    }
#pragma unroll
    for (int dt = 0; dt < 8; dt++) {
#pragma unroll
      for (int r = 0; r < 4; r++) o[dt][r] *= scale[r];
    }
    // --- P -> LDS (C/D layout -> A-frag layout round trip) ---
#pragma unroll
    for (int r = 0; r < 4; r++) {
      pbuf[lg * 4 + r][lr]      = f2bf(p0[r]);
      pbuf[lg * 4 + r][16 + lr] = f2bf(p1[r]);
    }
    __syncthreads();
    bf16x8 pf = *(const bf16x8*)&pbuf[lr][lg * 8];
    // --- PV: O[16][128] += P[16][32] @ V[32][128] ---
#pragma unroll
    for (int dt = 0; dt < 8; dt++) {
      const ushort* vp = VT + (size_t)(dt * 16 + lr) * N_NODES + k0 + lg * 8;
      bf16x8 vf = *(const bf16x8*)vp;
      o[dt] = __builtin_amdgcn_mfma_f32_16x16x32_bf16(pf, vf, o[dt], 0, 0, 0);
    }
    __syncthreads();
#pragma unroll
    for (int r = 0; r < 4; r++) { av0[r] = nv0[r]; av1[r] = nv1[r]; }
  }

  const int ps = b * KS0 + ks;
#pragma unroll
  for (int r = 0; r < 4; r++) {
    const size_t row = (size_t)ps * N_NODES + qrow_base + r;
    if (lr == 0) { pm0[row] = m[r]; pl0[row] = lsum[r]; }
#pragma unroll
    for (int dt = 0; dt < 8; dt++)
      pO[row * H_DIM + dt * 16 + lr] = o[dt][r];
  }
}

// ---------------------------------------------------------------------------
// K2b: merge the KS0 K-split partials -> o0[b][q][128]
// ---------------------------------------------------------------------------
__global__ __launch_bounds__(128) void combine0_kernel(
    const float* __restrict__ pm0, const float* __restrict__ pl0,
    const float* __restrict__ pO, float* __restrict__ o0)
{
  const int q = blockIdx.x;
  const int b = blockIdx.y;
  const int t = threadIdx.x;
  float mv[KS0], lv[KS0];
  float M = -1e30f;
#pragma unroll
  for (int ks = 0; ks < KS0; ks++) {
    const size_t row = (size_t)(b * KS0 + ks) * N_NODES + q;
    mv[ks] = pm0[row]; lv[ks] = pl0[row];
    M = fmaxf(M, mv[ks]);
  }
  float L = 0.f, O = 0.f;
#pragma unroll
  for (int ks = 0; ks < KS0; ks++) {
    const size_t row = (size_t)(b * KS0 + ks) * N_NODES + q;
    float wk = exp2f(mv[ks] - M);
    L = fmaf(wk, lv[ks], L);
    O = fmaf(wk, pO[row * H_DIM + t], O);
  }
  o0[((size_t)b * N_NODES + q) * H_DIM + t] = O / L;
}

// ---------------------------------------------------------------------------
// K3: h_comb = sum_b softmax(g0)_b * relu(o0_b + b0_b); hb = h_comb @ W1 (x3);
//     row norms over 16 dims -> hn1.
// ---------------------------------------------------------------------------
__global__ __launch_bounds__(128) void mix1_kernel(
    const float* __restrict__ o0,
    const float* __restrict__ bl0, const float* __restrict__ bh0,
    const float* __restrict__ bm0,
    const float* __restrict__ Wl1, const float* __restrict__ Wh1,
    const float* __restrict__ Wm1,
    const float* __restrict__ g0,
    float* __restrict__ hb, float* __restrict__ hn1)
{
  const int q = blockIdx.x;
  const int t = threadIdx.x;
  float ga = g0[0], gb = g0[1], gc = g0[2];
  float gm = fmaxf(ga, fmaxf(gb, gc));
  float e0 = expf(ga - gm), e1 = expf(gb - gm), e2 = expf(gc - gm);
  float ei = 1.0f / (e0 + e1 + e2);
  const size_t ND = (size_t)N_NODES * H_DIM;

  __shared__ float hc[H_DIM];
  float v = e0 * ei * fmaxf(o0[(size_t)q * H_DIM + t] + bl0[t], 0.f)
          + e1 * ei * fmaxf(o0[ND + (size_t)q * H_DIM + t] + bh0[t], 0.f)
          + e2 * ei * fmaxf(o0[2 * ND + (size_t)q * H_DIM + t] + bm0[t], 0.f);
  hc[t] = v;
  __syncthreads();

  __shared__ float shb[48];
  if (t < 48) {
    const int b = t >> 4, j = t & 15;
    const float* W = (b == 0) ? Wl1 : (b == 1) ? Wh1 : Wm1;
    float s = 0.f;
    for (int k = 0; k < H_DIM; k++) s = fmaf(hc[k], W[k * C_DIM + j], s);
    shb[t] = s;
  }
  __syncthreads();
  __shared__ float rns[3];
  if (t < 3) {
    float s = 0.f;
#pragma unroll
    for (int j = 0; j < C_DIM; j++) { float u = shb[t * C_DIM + j]; s = fmaf(u, u, s); }
    rns[t] = 1.0f / fmaxf(sqrtf(s), EPSF);
  }
  __syncthreads();
  if (t < 48) {
    const int b = t >> 4, j = t & 15;
    size_t idx = ((size_t)b * N_NODES + q) * C_DIM + j;
    hb[idx] = shb[t];
    hn1[idx] = shb[t] * rns[b];
  }
}

// ---------------------------------------------------------------------------
// K4: flash attention layer 1, D=16, f32 vector, thread-per-q-row, K-split 16.
// ---------------------------------------------------------------------------
#define KCH 256
__global__ __launch_bounds__(256) void flash1_kernel(
    const float* __restrict__ hn1, const float* __restrict__ hb,
    const float* __restrict__ adj_l, const float* __restrict__ adj_h,
    const float* __restrict__ adj_m,
    float* __restrict__ pm, float* __restrict__ pl, float* __restrict__ pacc)
{
  const int tid = threadIdx.x;
  const int q = blockIdx.x * 256 + tid;
  const int ks = blockIdx.y;
  const int b = blockIdx.z;
  const float* adj = (b == 0) ? adj_l : (b == 1) ? adj_h : adj_m;
  const float* Qn = hn1 + (size_t)b * N_NODES * C_DIM;
  const float* V  = hb  + (size_t)b * N_NODES * C_DIM;

  f32x4 qv[4];
  {
    const f32x4* p = (const f32x4*)(Qn + (size_t)q * C_DIM);
#pragma unroll
    for (int i = 0; i < 4; i++) qv[i] = p[i];
  }

  __shared__ __align__(16) float skn[KCH][C_DIM];
  __shared__ __align__(16) float sv[KCH][C_DIM];
  const int k0 = ks * KCH;
  {
    const f32x4* src1 = (const f32x4*)(Qn + (size_t)k0 * C_DIM);
    const f32x4* src2 = (const f32x4*)(V + (size_t)k0 * C_DIM);
    f32x4* d1 = (f32x4*)&skn[0][0];
    f32x4* d2 = (f32x4*)&sv[0][0];
    for (int i = tid; i < KCH * C_DIM / 4; i += 256) { d1[i] = src1[i]; d2[i] = src2[i]; }
  }
  __syncthreads();

  float m = -1e30f, l = 0.f;
  f32x4 acc[4];
#pragma unroll
  for (int i = 0; i < 4; i++) acc[i] = (f32x4){0.f, 0.f, 0.f, 0.f};

  const float* arow = adj + (size_t)q * N_NODES + k0;
  for (int kk = 0; kk < KCH; kk += 4) {
    f32x4 av = *(const f32x4*)(arow + kk);
#pragma unroll
    for (int u = 0; u < 4; u++) {
      const int k = kk + u;
      float s = 0.f;
#pragma unroll
      for (int i = 0; i < 4; i++) {
        f32x4 kv = ((const f32x4*)&skn[k][0])[i];
        s += qv[i][0] * kv[0] + qv[i][1] * kv[1] + qv[i][2] * kv[2] + qv[i][3] * kv[3];
      }
      s = fmaf(s, LOG2E, log2f(av[u] + EPSF));
      float mn = fmaxf(m, s);
      float sc = exp2f(m - mn);
      float p = exp2f(s - mn);
      m = mn;
      l = fmaf(l, sc, p);
#pragma unroll
      for (int i = 0; i < 4; i++) {
        f32x4 vv = ((const f32x4*)&sv[k][0])[i];
        acc[i] = acc[i] * sc + p * vv;
      }
    }
  }

  const size_t pidx = (size_t)(b * 16 + ks) * N_NODES + q;
  pm[pidx] = m;
  pl[pidx] = l;
  f32x4* pa = (f32x4*)(pacc + pidx * C_DIM);
#pragma unroll
  for (int i = 0; i < 4; i++) pa[i] = acc[i];
}

// ---------------------------------------------------------------------------
// K5: merge the 16 K-split partials per (branch, row).
// ---------------------------------------------------------------------------
__global__ __launch_bounds__(256) void combine1_kernel(
    const float* __restrict__ pm, const float* __restrict__ pl,
    const float* __restrict__ pacc, float* __restrict__ o1)
{
  const int q = blockIdx.x * 256 + threadIdx.x;
  const int b = blockIdx.y;
  float ms[16];
  float M = -1e30f;
#pragma unroll
  for (int ks = 0; ks < 16; ks++) {
    ms[ks] = pm[(size_t)(b * 16 + ks) * N_NODES + q];
    M = fmaxf(M, ms[ks]);
  }
  float L = 0.f;
  f32x4 out0 = (f32x4){0,0,0,0}, out1 = (f32x4){0,0,0,0},
        out2 = (f32x4){0,0,0,0}, out3 = (f32x4){0,0,0,0};
#pragma unroll
  for (int ks = 0; ks < 16; ks++) {
    const size_t pidx = (size_t)(b * 16 + ks) * N_NODES + q;
    float wk = exp2f(ms[ks] - M);
    L = fmaf(wk, pl[pidx], L);
    const f32x4* pa = (const f32x4*)(pacc + pidx * C_DIM);
    out0 += wk * pa[0]; out1 += wk * pa[1]; out2 += wk * pa[2]; out3 += wk * pa[3];
  }
  float invL = 1.0f / L;
  f32x4* dst = (f32x4*)(o1 + ((size_t)b * N_NODES + q) * C_DIM);
  dst[0] = out0 * invL; dst[1] = out1 * invL; dst[2] = out2 * invL; dst[3] = out3 * invL;
}

// ---------------------------------------------------------------------------
// K6: add biases, softmax(g1)-weighted branch mix, log_softmax over 16.
// ---------------------------------------------------------------------------
__global__ __launch_bounds__(256) void final_kernel(
    const float* __restrict__ o1,
    const float* __restrict__ bl1, const float* __restrict__ bh1,
    const float* __restrict__ bm1,
    const float* __restrict__ g1, float* __restrict__ out)
{
  const int q = blockIdx.x * 256 + threadIdx.x;
  float ga = g1[0], gb = g1[1], gc = g1[2];
  float gm = fmaxf(ga, fmaxf(gb, gc));
  float e0 = expf(ga - gm), e1 = expf(gb - gm), e2 = expf(gc - gm);
  float ei = 1.0f / (e0 + e1 + e2);
  float w0 = e0 * ei, w1 = e1 * ei, w2 = e2 * ei;
  const size_t NC = (size_t)N_NODES * C_DIM;

  float v[16];
#pragma unroll
  for (int i = 0; i < 4; i++) {
    f32x4 a = ((const f32x4*)(o1 + (size_t)q * C_DIM))[i];
    f32x4 bA = ((const f32x4*)(o1 + NC + (size_t)q * C_DIM))[i];
    f32x4 c = ((const f32x4*)(o1 + 2 * NC + (size_t)q * C_DIM))[i];
    f32x4 xl = ((const f32x4*)bl1)[i];
    f32x4 xh = ((const f32x4*)bh1)[i];
    f32x4 xm = ((const f32x4*)bm1)[i];
#pragma unroll
    for (int j = 0; j < 4; j++)
      v[i * 4 + j] = w0 * (a[j] + xl[j]) + w1 * (bA[j] + xh[j]) + w2 * (c[j] + xm[j]);
  }
  float mx = -1e30f;
#pragma unroll
  for (int j = 0; j < 16; j++) mx = fmaxf(mx, v[j]);
  float se = 0.f;
#pragma unroll
  for (int j = 0; j < 16; j++) se += expf(v[j] - mx);
  float lse = mx + logf(se);
  f32x4* dst = (f32x4*)(out + (size_t)q * C_DIM);
#pragma unroll
  for (int i = 0; i < 4; i++) {
    f32x4 r;
#pragma unroll
    for (int j = 0; j < 4; j++) r[j] = v[i * 4 + j] - lse;
    dst[i] = r;
  }
}

// ---------------------------------------------------------------------------
extern "C" void kernel_launch(void* const* d_in, const int* in_sizes, int n_in,
                              void* d_out, int out_size, void* d_ws, size_t ws_size,
                              hipStream_t stream) {
  (void)in_sizes; (void)n_in; (void)out_size; (void)ws_size;
  const float* x     = (const float*)d_in[0];
  const float* adj_l = (const float*)d_in[1];
  const float* adj_h = (const float*)d_in[2];
  const float* adj_m = (const float*)d_in[3];
  const float* w_l0  = (const float*)d_in[4];
  const float* b_l0  = (const float*)d_in[5];
  const float* w_h0  = (const float*)d_in[6];
  const float* b_h0  = (const float*)d_in[7];
  const float* w_m0  = (const float*)d_in[8];
  const float* b_m0  = (const float*)d_in[9];
  const float* w_l1  = (const float*)d_in[10];
  const float* b_l1  = (const float*)d_in[11];
  const float* w_h1  = (const float*)d_in[12];
  const float* b_h1  = (const float*)d_in[13];
  const float* w_m1  = (const float*)d_in[14];
  const float* b_m1  = (const float*)d_in[15];
  const float* g0    = (const float*)d_in[16];
  const float* g1    = (const float*)d_in[17];
  float* out = (float*)d_out;

  char* ws = (char*)d_ws;
  // persistent across phases:
  ushort* hn  = (ushort*)(ws);                  // [0, 3MB)
  ushort* hvT = (ushort*)(ws + (3u << 20));     // [3MB, 6MB)
  float*  o0  = (float*)(ws + (6u << 20));      // [6MB, 12MB)
  // phase A (layer-0 partials), dead after combine0:
  float*  pm0 = (float*)(ws + (12u << 20));                    // 196KB
  float*  pl0 = (float*)(ws + (12u << 20) + (256u << 10));     // 196KB
  float*  pO  = (float*)(ws + (12u << 20) + (512u << 10));     // 25.2MB -> ends ~37.7MB
  // phase B (layer-1 scratch), reuses phase-A region:
  float*  hb  = (float*)(ws + (12u << 20));             // 768KB
  float*  hn1 = (float*)(ws + (12u << 20) + 786432);    // 768KB
  float*  pm  = (float*)(ws + (12u << 20) + 2 * 786432);
  float*  pl  = (float*)(ws + (12u << 20) + 3 * 786432);
  float*  pacc= (float*)(ws + (12u << 20) + 4 * 786432);          // 12MB
  float*  o1  = (float*)(ws + (12u << 20) + 4 * 786432 + (12u << 20)); // 768KB

  proj0_kernel<<<dim3(512), dim3(128), 0, stream>>>(x, w_l0, w_h0, w_m0, hn, hvT);
  flash0_kernel<<<dim3(256, KS0, 3), dim3(64), 0, stream>>>(hn, hvT, adj_l, adj_h, adj_m,
                                                            pm0, pl0, pO);
  combine0_kernel<<<dim3(4096, 3), dim3(128), 0, stream>>>(pm0, pl0, pO, o0);
  mix1_kernel<<<dim3(4096), dim3(128), 0, stream>>>(o0, b_l0, b_h0, b_m0,
                                                    w_l1, w_h1, w_m1, g0, hb, hn1);
  flash1_kernel<<<dim3(16, 16, 3), dim3(256), 0, stream>>>(hn1, hb, adj_l, adj_h, adj_m,
                                                           pm, pl, pacc);
  combine1_kernel<<<dim3(16, 3), dim3(256), 0, stream>>>(pm, pl, pacc, o1);
  final_kernel<<<dim3(16), dim3(256), 0, stream>>>(o1, b_l1, b_h1, b_m1, g1, out);
}

// Round 3
// 396.747 us; speedup vs baseline: 1.4255x; 1.0139x over previous
//
#include <hip/hip_runtime.h>

#define N_NODES 4096
#define F_IN 512
#define H_DIM 128
#define C_DIM 16
#define EPSF 1e-8f
#define LOG2E 1.4426950408889634f
#define SMAX 2.0f   // static softmax max: logits = cos/tau*log2e + log2(adj+eps) < 2 always

typedef __attribute__((ext_vector_type(8))) short bf16x8;
typedef __attribute__((ext_vector_type(4))) float f32x4;

__device__ __forceinline__ ushort f2bf(float f){
  union { float f; unsigned u; } v; v.f = f;
  unsigned u = v.u;
  return (ushort)((u + 0x7fffu + ((u >> 16) & 1u)) >> 16);
}

// ---------------------------------------------------------------------------
// K1: h = x @ W0 for 3 branches; row norms; write hn (bf16, row-major) and
//     hvT (bf16, transposed [3][128][4096]).
// ---------------------------------------------------------------------------
__global__ __launch_bounds__(128) void proj0_kernel(
    const float* __restrict__ x,
    const float* __restrict__ Wl, const float* __restrict__ Wh,
    const float* __restrict__ Wm,
    ushort* __restrict__ hn, ushort* __restrict__ hvT)
{
  const int t = threadIdx.x;
  const int r0 = blockIdx.x * 8;
  __shared__ float xs[8][F_IN];
  for (int i = t; i < 8 * F_IN; i += 128)
    xs[i >> 9][i & 511] = x[(size_t)(r0 + (i >> 9)) * F_IN + (i & 511)];
  __syncthreads();

  float acc0[8], acc1[8], acc2[8];
#pragma unroll
  for (int r = 0; r < 8; r++) { acc0[r] = 0.f; acc1[r] = 0.f; acc2[r] = 0.f; }

  for (int k = 0; k < F_IN; k++) {
    float wl = Wl[k * H_DIM + t];
    float wh = Wh[k * H_DIM + t];
    float wm = Wm[k * H_DIM + t];
#pragma unroll
    for (int r = 0; r < 8; r++) {
      float xv = xs[r][k];
      acc0[r] = fmaf(xv, wl, acc0[r]);
      acc1[r] = fmaf(xv, wh, acc1[r]);
      acc2[r] = fmaf(xv, wm, acc2[r]);
    }
  }

  __shared__ float red[24][2];
  const int wv = t >> 6;
  const int lane = t & 63;

#define REDUCE_BRANCH(ACC, B)                                        \
  _Pragma("unroll")                                                  \
  for (int r = 0; r < 8; r++) {                                      \
    float v = ACC[r] * ACC[r];                                       \
    v += __shfl_down(v, 32); v += __shfl_down(v, 16);                \
    v += __shfl_down(v, 8);  v += __shfl_down(v, 4);                 \
    v += __shfl_down(v, 2);  v += __shfl_down(v, 1);                 \
    if (lane == 0) red[(B) * 8 + r][wv] = v;                         \
  }
  REDUCE_BRANCH(acc0, 0)
  REDUCE_BRANCH(acc1, 1)
  REDUCE_BRANCH(acc2, 2)
  __syncthreads();

#define WRITE_BRANCH(ACC, B)                                                   \
  _Pragma("unroll")                                                            \
  for (int r = 0; r < 8; r++) {                                                \
    float nrm = sqrtf(red[(B) * 8 + r][0] + red[(B) * 8 + r][1]);              \
    float rn = 1.0f / fmaxf(nrm, EPSF);                                        \
    float h = ACC[r];                                                          \
    hn[((size_t)(B) * N_NODES + r0 + r) * H_DIM + t] = f2bf(h * rn);           \
    hvT[((size_t)(B) * H_DIM + t) * N_NODES + r0 + r] = f2bf(h);               \
  }
  WRITE_BRANCH(acc0, 0)
  WRITE_BRANCH(acc1, 1)
  WRITE_BRANCH(acc2, 2)
#undef REDUCE_BRANCH
#undef WRITE_BRANCH
}

// ---------------------------------------------------------------------------
// K2: flash attention layer 0, D=128, bf16 MFMA, K-split nks ways, static max.
//     Each wave: 16 q-rows x klen K-cols. Writes unnormalized partials
//     (l, O[16][128]); p = exp2(logit - SMAX) needs no rescaling ever.
// ---------------------------------------------------------------------------
__global__ __launch_bounds__(64) void flash0_kernel(
    const ushort* __restrict__ hn, const ushort* __restrict__ hvT,
    const float* __restrict__ adj_l, const float* __restrict__ adj_h,
    const float* __restrict__ adj_m,
    float* __restrict__ pl0, float* __restrict__ pO,
    int nks, int klen)
{
  const int lane = threadIdx.x;
  const int lr = lane & 15;
  const int lg = lane >> 4;
  const int ks = blockIdx.y;
  const int b = blockIdx.z;
  const int q0 = blockIdx.x * 16;
  const float* adj = (b == 0) ? adj_l : (b == 1) ? adj_h : adj_m;
  const ushort* Q = hn + (size_t)b * N_NODES * H_DIM;
  const ushort* VT = hvT + (size_t)b * H_DIM * N_NODES;
  const int kbase = ks * klen;
  const int nt = klen >> 5;

  bf16x8 qf[4];
  {
    const ushort* qp = Q + (size_t)(q0 + lr) * H_DIM + lg * 8;
#pragma unroll
    for (int t = 0; t < 4; t++) qf[t] = *(const bf16x8*)(qp + 32 * t);
  }

  f32x4 o[8];
#pragma unroll
  for (int dt = 0; dt < 8; dt++) o[dt] = (f32x4){0.f, 0.f, 0.f, 0.f};
  float lsum[4] = {0.f, 0.f, 0.f, 0.f};

  __shared__ ushort pbuf[16][40];

  const int qrow_base = q0 + lg * 4;

  const float* ar[4];
#pragma unroll
  for (int r = 0; r < 4; r++)
    ar[r] = adj + (size_t)(qrow_base + r) * N_NODES + kbase;

  float av0[4], av1[4];
#pragma unroll
  for (int r = 0; r < 4; r++) { av0[r] = ar[r][lr]; av1[r] = ar[r][16 + lr]; }

  for (int t = 0; t < nt; t++) {
    const int k0 = kbase + t * 32;
    // prefetch next tile's adj
    float nv0[4], nv1[4];
    if (t + 1 < nt) {
#pragma unroll
      for (int r = 0; r < 4; r++) {
        nv0[r] = ar[r][(t + 1) * 32 + lr];
        nv1[r] = ar[r][(t + 1) * 32 + 16 + lr];
      }
    }
    // --- QK^T (two 16x16 S tiles) ---
    f32x4 s0 = (f32x4){0.f, 0.f, 0.f, 0.f};
    f32x4 s1 = (f32x4){0.f, 0.f, 0.f, 0.f};
    {
      const ushort* kp0 = Q + (size_t)(k0 + lr) * H_DIM + lg * 8;
      const ushort* kp1 = kp0 + 16 * H_DIM;
#pragma unroll
      for (int u = 0; u < 4; u++) {
        bf16x8 kf0 = *(const bf16x8*)(kp0 + 32 * u);
        bf16x8 kf1 = *(const bf16x8*)(kp1 + 32 * u);
        s0 = __builtin_amdgcn_mfma_f32_16x16x32_bf16(qf[u], kf0, s0, 0, 0, 0);
        s1 = __builtin_amdgcn_mfma_f32_16x16x32_bf16(qf[u], kf1, s1, 0, 0, 0);
      }
    }
    // --- bias + softmax numerator, static max (no reductions, no rescale) ---
    float p0[4], p1[4];
#pragma unroll
    for (int r = 0; r < 4; r++) {
      float l0 = fmaf(s0[r], LOG2E, log2f(av0[r] + EPSF));
      float l1 = fmaf(s1[r], LOG2E, log2f(av1[r] + EPSF));
      p0[r] = exp2f(l0 - SMAX);
      p1[r] = exp2f(l1 - SMAX);
      lsum[r] += p0[r] + p1[r];
    }
    // --- P -> LDS (C/D layout -> A-frag layout round trip) ---
#pragma unroll
    for (int r = 0; r < 4; r++) {
      pbuf[lg * 4 + r][lr]      = f2bf(p0[r]);
      pbuf[lg * 4 + r][16 + lr] = f2bf(p1[r]);
    }
    __syncthreads();
    bf16x8 pf = *(const bf16x8*)&pbuf[lr][lg * 8];
    // --- PV: O[16][128] += P[16][32] @ V[32][128] ---
#pragma unroll
    for (int dt = 0; dt < 8; dt++) {
      const ushort* vp = VT + (size_t)(dt * 16 + lr) * N_NODES + k0 + lg * 8;
      bf16x8 vf = *(const bf16x8*)vp;
      o[dt] = __builtin_amdgcn_mfma_f32_16x16x32_bf16(pf, vf, o[dt], 0, 0, 0);
    }
    __syncthreads();
#pragma unroll
    for (int r = 0; r < 4; r++) { av0[r] = nv0[r]; av1[r] = nv1[r]; }
  }

  const int ps = b * nks + ks;
#pragma unroll
  for (int r = 0; r < 4; r++) {
    const size_t row = (size_t)ps * N_NODES + qrow_base + r;
    // reduce the per-lane partial denominator across the 16-lane group
    float psum = lsum[r];
#pragma unroll
    for (int d = 1; d < 16; d <<= 1) psum += __shfl_xor(psum, d);
    if (lr == 0) pl0[row] = psum;
#pragma unroll
    for (int dt = 0; dt < 8; dt++)
      pO[row * H_DIM + dt * 16 + lr] = o[dt][r];
  }
}

// ---------------------------------------------------------------------------
// K2b: merge the nks K-split partials (plain sums; static max) -> o0
// ---------------------------------------------------------------------------
__global__ __launch_bounds__(128) void combine0_kernel(
    const float* __restrict__ pl0, const float* __restrict__ pO,
    float* __restrict__ o0, int nks)
{
  const int q = blockIdx.x;
  const int b = blockIdx.y;
  const int t = threadIdx.x;
  float L = 0.f, O = 0.f;
  for (int ks = 0; ks < nks; ks++) {
    const size_t row = (size_t)(b * nks + ks) * N_NODES + q;
    L += pl0[row];
    O += pO[row * H_DIM + t];
  }
  o0[((size_t)b * N_NODES + q) * H_DIM + t] = O / L;
}

// ---------------------------------------------------------------------------
// K3: h_comb = sum_b softmax(g0)_b * relu(o0_b + b0_b); hb = h_comb @ W1 (x3);
//     row norms over 16 dims -> hn1.
// ---------------------------------------------------------------------------
__global__ __launch_bounds__(128) void mix1_kernel(
    const float* __restrict__ o0,
    const float* __restrict__ bl0, const float* __restrict__ bh0,
    const float* __restrict__ bm0,
    const float* __restrict__ Wl1, const float* __restrict__ Wh1,
    const float* __restrict__ Wm1,
    const float* __restrict__ g0,
    float* __restrict__ hb, float* __restrict__ hn1)
{
  const int q = blockIdx.x;
  const int t = threadIdx.x;
  float ga = g0[0], gb = g0[1], gc = g0[2];
  float gm = fmaxf(ga, fmaxf(gb, gc));
  float e0 = expf(ga - gm), e1 = expf(gb - gm), e2 = expf(gc - gm);
  float ei = 1.0f / (e0 + e1 + e2);
  const size_t ND = (size_t)N_NODES * H_DIM;

  __shared__ float hc[H_DIM];
  float v = e0 * ei * fmaxf(o0[(size_t)q * H_DIM + t] + bl0[t], 0.f)
          + e1 * ei * fmaxf(o0[ND + (size_t)q * H_DIM + t] + bh0[t], 0.f)
          + e2 * ei * fmaxf(o0[2 * ND + (size_t)q * H_DIM + t] + bm0[t], 0.f);
  hc[t] = v;
  __syncthreads();

  __shared__ float shb[48];
  if (t < 48) {
    const int b = t >> 4, j = t & 15;
    const float* W = (b == 0) ? Wl1 : (b == 1) ? Wh1 : Wm1;
    float s = 0.f;
    for (int k = 0; k < H_DIM; k++) s = fmaf(hc[k], W[k * C_DIM + j], s);
    shb[t] = s;
  }
  __syncthreads();
  __shared__ float rns[3];
  if (t < 3) {
    float s = 0.f;
#pragma unroll
    for (int j = 0; j < C_DIM; j++) { float u = shb[t * C_DIM + j]; s = fmaf(u, u, s); }
    rns[t] = 1.0f / fmaxf(sqrtf(s), EPSF);
  }
  __syncthreads();
  if (t < 48) {
    const int b = t >> 4, j = t & 15;
    size_t idx = ((size_t)b * N_NODES + q) * C_DIM + j;
    hb[idx] = shb[t];
    hn1[idx] = shb[t] * rns[b];
  }
}

// ---------------------------------------------------------------------------
// K4: flash attention layer 1, D=16, f32 vector, thread-per-q-row, K-split 16,
//     static max (no online rescale -> no serial chain).
// ---------------------------------------------------------------------------
#define KCH 256
__global__ __launch_bounds__(256) void flash1_kernel(
    const float* __restrict__ hn1, const float* __restrict__ hb,
    const float* __restrict__ adj_l, const float* __restrict__ adj_h,
    const float* __restrict__ adj_m,
    float* __restrict__ pl, float* __restrict__ pacc)
{
  const int tid = threadIdx.x;
  const int q = blockIdx.x * 256 + tid;
  const int ks = blockIdx.y;
  const int b = blockIdx.z;
  const float* adj = (b == 0) ? adj_l : (b == 1) ? adj_h : adj_m;
  const float* Qn = hn1 + (size_t)b * N_NODES * C_DIM;
  const float* V  = hb  + (size_t)b * N_NODES * C_DIM;

  f32x4 qv[4];
  {
    const f32x4* p = (const f32x4*)(Qn + (size_t)q * C_DIM);
#pragma unroll
    for (int i = 0; i < 4; i++) qv[i] = p[i];
  }

  __shared__ __align__(16) float skn[KCH][C_DIM];
  __shared__ __align__(16) float sv[KCH][C_DIM];
  const int k0 = ks * KCH;
  {
    const f32x4* src1 = (const f32x4*)(Qn + (size_t)k0 * C_DIM);
    const f32x4* src2 = (const f32x4*)(V + (size_t)k0 * C_DIM);
    f32x4* d1 = (f32x4*)&skn[0][0];
    f32x4* d2 = (f32x4*)&sv[0][0];
    for (int i = tid; i < KCH * C_DIM / 4; i += 256) { d1[i] = src1[i]; d2[i] = src2[i]; }
  }
  __syncthreads();

  float l = 0.f;
  f32x4 acc[4];
#pragma unroll
  for (int i = 0; i < 4; i++) acc[i] = (f32x4){0.f, 0.f, 0.f, 0.f};

  const float* arow = adj + (size_t)q * N_NODES + k0;
  for (int kk = 0; kk < KCH; kk += 4) {
    f32x4 av = *(const f32x4*)(arow + kk);
#pragma unroll
    for (int u = 0; u < 4; u++) {
      const int k = kk + u;
      float s = 0.f;
#pragma unroll
      for (int i = 0; i < 4; i++) {
        f32x4 kv = ((const f32x4*)&skn[k][0])[i];
        s += qv[i][0] * kv[0] + qv[i][1] * kv[1] + qv[i][2] * kv[2] + qv[i][3] * kv[3];
      }
      s = fmaf(s, LOG2E, log2f(av[u] + EPSF));
      float p = exp2f(s - SMAX);
      l += p;
#pragma unroll
      for (int i = 0; i < 4; i++) {
        f32x4 vv = ((const f32x4*)&sv[k][0])[i];
        acc[i] += p * vv;
      }
    }
  }

  const size_t pidx = (size_t)(b * 16 + ks) * N_NODES + q;
  pl[pidx] = l;
  f32x4* pa = (f32x4*)(pacc + pidx * C_DIM);
#pragma unroll
  for (int i = 0; i < 4; i++) pa[i] = acc[i];
}

// ---------------------------------------------------------------------------
// K5: merge the 16 K-split partials per (branch, row) — plain sums.
// ---------------------------------------------------------------------------
__global__ __launch_bounds__(256) void combine1_kernel(
    const float* __restrict__ pl, const float* __restrict__ pacc,
    float* __restrict__ o1)
{
  const int q = blockIdx.x * 256 + threadIdx.x;
  const int b = blockIdx.y;
  float L = 0.f;
  f32x4 out0 = (f32x4){0,0,0,0}, out1 = (f32x4){0,0,0,0},
        out2 = (f32x4){0,0,0,0}, out3 = (f32x4){0,0,0,0};
#pragma unroll
  for (int ks = 0; ks < 16; ks++) {
    const size_t pidx = (size_t)(b * 16 + ks) * N_NODES + q;
    L += pl[pidx];
    const f32x4* pa = (const f32x4*)(pacc + pidx * C_DIM);
    out0 += pa[0]; out1 += pa[1]; out2 += pa[2]; out3 += pa[3];
  }
  float invL = 1.0f / L;
  f32x4* dst = (f32x4*)(o1 + ((size_t)b * N_NODES + q) * C_DIM);
  dst[0] = out0 * invL; dst[1] = out1 * invL; dst[2] = out2 * invL; dst[3] = out3 * invL;
}

// ---------------------------------------------------------------------------
// K6: add biases, softmax(g1)-weighted branch mix, log_softmax over 16.
// ---------------------------------------------------------------------------
__global__ __launch_bounds__(256) void final_kernel(
    const float* __restrict__ o1,
    const float* __restrict__ bl1, const float* __restrict__ bh1,
    const float* __restrict__ bm1,
    const float* __restrict__ g1, float* __restrict__ out)
{
  const int q = blockIdx.x * 256 + threadIdx.x;
  float ga = g1[0], gb = g1[1], gc = g1[2];
  float gm = fmaxf(ga, fmaxf(gb, gc));
  float e0 = expf(ga - gm), e1 = expf(gb - gm), e2 = expf(gc - gm);
  float ei = 1.0f / (e0 + e1 + e2);
  float w0 = e0 * ei, w1 = e1 * ei, w2 = e2 * ei;
  const size_t NC = (size_t)N_NODES * C_DIM;

  float v[16];
#pragma unroll
  for (int i = 0; i < 4; i++) {
    f32x4 a = ((const f32x4*)(o1 + (size_t)q * C_DIM))[i];
    f32x4 bA = ((const f32x4*)(o1 + NC + (size_t)q * C_DIM))[i];
    f32x4 c = ((const f32x4*)(o1 + 2 * NC + (size_t)q * C_DIM))[i];
    f32x4 xl = ((const f32x4*)bl1)[i];
    f32x4 xh = ((const f32x4*)bh1)[i];
    f32x4 xm = ((const f32x4*)bm1)[i];
#pragma unroll
    for (int j = 0; j < 4; j++)
      v[i * 4 + j] = w0 * (a[j] + xl[j]) + w1 * (bA[j] + xh[j]) + w2 * (c[j] + xm[j]);
  }
  float mx = -1e30f;
#pragma unroll
  for (int j = 0; j < 16; j++) mx = fmaxf(mx, v[j]);
  float se = 0.f;
#pragma unroll
  for (int j = 0; j < 16; j++) se += expf(v[j] - mx);
  float lse = mx + logf(se);
  f32x4* dst = (f32x4*)(out + (size_t)q * C_DIM);
#pragma unroll
  for (int i = 0; i < 4; i++) {
    f32x4 r;
#pragma unroll
    for (int j = 0; j < 4; j++) r[j] = v[i * 4 + j] - lse;
    dst[i] = r;
  }
}

// ---------------------------------------------------------------------------
extern "C" void kernel_launch(void* const* d_in, const int* in_sizes, int n_in,
                              void* d_out, int out_size, void* d_ws, size_t ws_size,
                              hipStream_t stream) {
  (void)in_sizes; (void)n_in; (void)out_size;
  const float* x     = (const float*)d_in[0];
  const float* adj_l = (const float*)d_in[1];
  const float* adj_h = (const float*)d_in[2];
  const float* adj_m = (const float*)d_in[3];
  const float* w_l0  = (const float*)d_in[4];
  const float* b_l0  = (const float*)d_in[5];
  const float* w_h0  = (const float*)d_in[6];
  const float* b_h0  = (const float*)d_in[7];
  const float* w_m0  = (const float*)d_in[8];
  const float* b_m0  = (const float*)d_in[9];
  const float* w_l1  = (const float*)d_in[10];
  const float* b_l1  = (const float*)d_in[11];
  const float* w_h1  = (const float*)d_in[12];
  const float* b_h1  = (const float*)d_in[13];
  const float* w_m1  = (const float*)d_in[14];
  const float* b_m1  = (const float*)d_in[15];
  const float* g0    = (const float*)d_in[16];
  const float* g1    = (const float*)d_in[17];
  float* out = (float*)d_out;

  // K-split count for layer-0 flash: 8 if the workspace allows f32 partials
  // (needs ~63 MB), else 4 (needs ~38 MB, as validated in round 2).
  const int nks = (ws_size >= (64ull << 20)) ? 8 : 4;
  const int klen = N_NODES / nks;

  char* ws = (char*)d_ws;
  // persistent across phases:
  ushort* hn  = (ushort*)(ws);                  // [0, 3MB)
  ushort* hvT = (ushort*)(ws + (3u << 20));     // [3MB, 6MB)
  float*  o0  = (float*)(ws + (6u << 20));      // [6MB, 12MB)
  // phase A (layer-0 partials), dead after combine0:
  float*  pl0 = (float*)(ws + (12u << 20));                    // <=384KB
  float*  pO  = (float*)(ws + (12u << 20) + (512u << 10));     // <=50.4MB
  // phase B (layer-1 scratch), reuses phase-A region:
  float*  hb  = (float*)(ws + (12u << 20));             // 768KB
  float*  hn1 = (float*)(ws + (12u << 20) + 786432);    // 768KB
  float*  pl  = (float*)(ws + (12u << 20) + 2 * 786432);
  float*  pacc= (float*)(ws + (12u << 20) + 3 * 786432);          // 12MB
  float*  o1  = (float*)(ws + (12u << 20) + 3 * 786432 + (12u << 20)); // 768KB

  proj0_kernel<<<dim3(512), dim3(128), 0, stream>>>(x, w_l0, w_h0, w_m0, hn, hvT);
  flash0_kernel<<<dim3(256, nks, 3), dim3(64), 0, stream>>>(hn, hvT, adj_l, adj_h, adj_m,
                                                            pl0, pO, nks, klen);
  combine0_kernel<<<dim3(4096, 3), dim3(128), 0, stream>>>(pl0, pO, o0, nks);
  mix1_kernel<<<dim3(4096), dim3(128), 0, stream>>>(o0, b_l0, b_h0, b_m0,
                                                    w_l1, w_h1, w_m1, g0, hb, hn1);
  flash1_kernel<<<dim3(16, 16, 3), dim3(256), 0, stream>>>(hn1, hb, adj_l, adj_h, adj_m,
                                                           pl, pacc);
  combine1_kernel<<<dim3(16, 3), dim3(256), 0, stream>>>(pl, pacc, o1);
  final_kernel<<<dim3(16), dim3(256), 0, stream>>>(o1, b_l1, b_h1, b_m1, g1, out);
}